// Round 7
// baseline (470.009 us; speedup 1.0000x reference)
//
#include <hip/hip_runtime.h>

#define TPB 256
#define GRID1 1024
#define GRID2 1024
#define MSLICES 8

typedef __attribute__((ext_vector_type(8))) short short8;
typedef __attribute__((ext_vector_type(4))) float floatx4;

__device__ __forceinline__ unsigned short bf_trunc(float f){
    union { float f; unsigned u; } c; c.f = f;
    return (unsigned short)(c.u >> 16);
}
__device__ __forceinline__ unsigned short bf_rne(float f){
    union { float f; unsigned u; } c; c.f = f;
    unsigned r = c.u + 0x7fffu + ((c.u >> 16) & 1u);
    return (unsigned short)(r >> 16);
}
__device__ __forceinline__ unsigned pack_bf(float lo, float hi){
    union { float f; unsigned u; } a, b; a.f = lo; b.f = hi;
    return __builtin_amdgcn_perm(b.u, a.u, 0x07060302u);
}
__device__ __forceinline__ float bfbits(unsigned short u){
    union { unsigned u; float f; } c; c.u = ((unsigned)u) << 16; return c.f;
}

// ---------------------------------------------------------------------------
// prologue: batch boundaries lb[0..B] once.
// ---------------------------------------------------------------------------
__global__ void lb_kernel(const int* __restrict__ bidx, int* __restrict__ ws_lb,
                          int N, int B)
{
    const int t = threadIdx.x;
    if (t <= B){
        int lo = 0, hi = N;
        while (lo < hi){
            const int mid = (lo + hi) >> 1;
            if (bidx[mid] < t) lo = mid + 1; else hi = mid;
        }
        ws_lb[t] = lo;
    }
}

// ---------------------------------------------------------------------------
// R7 pass1: STATS-ONLY sweep. R6 showed every full sweep of feats costs
// ~150us regardless of payload (h-writes rode along free), so this round
// removes the h materialization entirely: BN stats of h are affine in feats
// stats -- var_c = (w_c^T M w_c)/N - (mu_f . w_c)^2 with M = sum f f^T.
// pass1 computes M via 9 MFMAs/32-row group (hi/lo double-bf16: products
// hi*hi + hi*lo + lo*hi, error ~1e-4 on var) + per-batch pooled sums.
// Writes only ~26KB of stats. Mask moved to pass2.
// M-fragments: transposed LDS reads from the staged (swizzled) group:
//   element (row,ch) at sw[row*32 + (((ch>>2)^(row&7))<<2) + (ch&3)]
//   A/B-frag for M_IJ: lane(p,q)[j] = G[row q*8+j][ch 16I+p]  (k = row)
//   D: M_IJ[4q+r][p] at lane(p,q) reg r (proven D-layout).
// ---------------------------------------------------------------------------
__global__ __launch_bounds__(TPB) void pass1_kernel(
    const float* __restrict__ feats, const int* __restrict__ ws_lb,
    float* __restrict__ ws_pool, float* __restrict__ ws_M,
    int N, int B)
{
    __shared__ float s_stage[TPB/64][1024];   // 4KB per wave
    __shared__ float s_pool[8][32];
    __shared__ float s_M[3][256];
    __shared__ int   s_lb[9];

    const int tid  = threadIdx.x;
    const int lane = tid & 63;
    const int wv   = tid >> 6;
    const int p = lane & 15;
    const int q = lane >> 4;

    ((float*)s_pool)[tid] = 0.f;
    for (int i = tid; i < 768; i += TPB) ((float*)s_M)[i] = 0.f;
    if (tid <= B) s_lb[tid] = ws_lb[tid];
    __syncthreads();

    float pacc[4] = {0,0,0,0};
    floatx4 acc00 = {0,0,0,0}, acc01 = {0,0,0,0}, acc11 = {0,0,0,0};

    const int ngroups = (N + 31) >> 5;
    const int nw  = gridDim.x * (TPB / 64);
    const int wid = blockIdx.x * (TPB / 64) + wv;
    const int g0  = (int)((long)wid       * ngroups / nw);
    const int gE  = (int)((long)(wid + 1) * ngroups / nw);

    int curb = 0;
    { const int r = g0 << 5; while (curb < B - 1 && r >= s_lb[curb + 1]) curb++; }
    int lbn = s_lb[curb + 1];

    float* sw = &s_stage[wv][0];
    const int wrow  = lane >> 3;
    const int wg    = (lane & 7) ^ wrow;
    const int cbase = (lane & 7) << 2;
    const int wo0 = ( 0 + wrow) * 32 + (wg << 2);
    const int wo1 = ( 8 + wrow) * 32 + (wg << 2);
    const int wo2 = (16 + wrow) * 32 + (wg << 2);
    const int wo3 = (24 + wrow) * 32 + (wg << 2);

    // prime group g0
    floatx4 sv0 = {0,0,0,0}, sv1 = {0,0,0,0}, sv2 = {0,0,0,0}, sv3 = {0,0,0,0};
    if (g0 < gE){
        const float* gp = feats + ((size_t)g0 << 10) + (lane << 2);
        const int r = (g0 << 5) + wrow;
        if (r + 24 < N){
            sv0 = *(const floatx4*)(gp);
            sv1 = *(const floatx4*)(gp + 256);
            sv2 = *(const floatx4*)(gp + 512);
            sv3 = *(const floatx4*)(gp + 768);
        } else {
            if (r      < N) sv0 = *(const floatx4*)(gp);
            if (r +  8 < N) sv1 = *(const floatx4*)(gp + 256);
            if (r + 16 < N) sv2 = *(const floatx4*)(gp + 512);
            if (r + 24 < N) sv3 = *(const floatx4*)(gp + 768);
        }
    }

    for (int g = g0; g < gE; ++g){
        // stage current group (wave-private, swizzled, no barriers)
        *(floatx4*)(sw + wo0) = sv0;
        *(floatx4*)(sw + wo1) = sv1;
        *(floatx4*)(sw + wo2) = sv2;
        *(floatx4*)(sw + wo3) = sv3;

        // prefetch next group
        floatx4 nv0 = {0,0,0,0}, nv1 = {0,0,0,0}, nv2 = {0,0,0,0}, nv3 = {0,0,0,0};
        if (g + 1 < gE){
            const float* gp = feats + ((size_t)(g + 1) << 10) + (lane << 2);
            const int r = ((g + 1) << 5) + wrow;
            if (r + 24 < N){
                nv0 = *(const floatx4*)(gp);
                nv1 = *(const floatx4*)(gp + 256);
                nv2 = *(const floatx4*)(gp + 512);
                nv3 = *(const floatx4*)(gp + 768);
            } else {
                if (r      < N) nv0 = *(const floatx4*)(gp);
                if (r +  8 < N) nv1 = *(const floatx4*)(gp + 256);
                if (r + 16 < N) nv2 = *(const floatx4*)(gp + 512);
                if (r + 24 < N) nv3 = *(const floatx4*)(gp + 768);
            }
        }

        // pooled accumulation from staged registers
        const int r0 = g << 5;
        if (r0 >= lbn){
#pragma unroll
            for (int j = 0; j < 4; ++j){
                if (pacc[j] != 0.f) atomicAdd(&s_pool[curb][cbase + j], pacc[j]);
                pacc[j] = 0.f;
            }
            do { curb++; } while (curb < B - 1 && r0 >= s_lb[curb + 1]);
            lbn = s_lb[curb + 1];
        }
        const bool slow = (r0 + 31 >= lbn) || (r0 + 31 >= N);

        if (!slow){
            pacc[0] += sv0[0] + sv1[0] + sv2[0] + sv3[0];
            pacc[1] += sv0[1] + sv1[1] + sv2[1] + sv3[1];
            pacc[2] += sv0[2] + sv1[2] + sv2[2] + sv3[2];
            pacc[3] += sv0[3] + sv1[3] + sv2[3] + sv3[3];
        } else {
#define SLOWROW(SV, L) { \
            const int row = r0 + (L * 8) + wrow; \
            if (row < N){ \
                int bl = curb; \
                for (int c = curb + 1; c < B; ++c) bl += (row >= s_lb[c]); \
                atomicAdd(&s_pool[bl][cbase + 0], SV[0]); \
                atomicAdd(&s_pool[bl][cbase + 1], SV[1]); \
                atomicAdd(&s_pool[bl][cbase + 2], SV[2]); \
                atomicAdd(&s_pool[bl][cbase + 3], SV[3]); \
            } }
            SLOWROW(sv0, 0) SLOWROW(sv1, 1) SLOWROW(sv2, 2) SLOWROW(sv3, 3)
#undef SLOWROW
        }

        // transposed hi/lo fragments for the channel-Gram (k = rows)
        short8 hi0, lo0, hi1, lo1;
#pragma unroll
        for (int j = 0; j < 8; ++j){
            const int row = q * 8 + j;
            const int e2  = row & 7;
            {
                const int c = p;
                const float v = sw[row * 32 + ((((c >> 2) ^ e2) << 2) + (c & 3))];
                const unsigned short hb = bf_trunc(v);
                hi0[j] = (short)hb;
                lo0[j] = (short)bf_trunc(v - bfbits(hb));
            }
            {
                const int c = 16 + p;
                const float v = sw[row * 32 + ((((c >> 2) ^ e2) << 2) + (c & 3))];
                const unsigned short hb = bf_trunc(v);
                hi1[j] = (short)hb;
                lo1[j] = (short)bf_trunc(v - bfbits(hb));
            }
        }

        acc00 = __builtin_amdgcn_mfma_f32_16x16x32_bf16(hi0, hi0, acc00, 0, 0, 0);
        acc00 = __builtin_amdgcn_mfma_f32_16x16x32_bf16(hi0, lo0, acc00, 0, 0, 0);
        acc00 = __builtin_amdgcn_mfma_f32_16x16x32_bf16(lo0, hi0, acc00, 0, 0, 0);
        acc01 = __builtin_amdgcn_mfma_f32_16x16x32_bf16(hi0, hi1, acc01, 0, 0, 0);
        acc01 = __builtin_amdgcn_mfma_f32_16x16x32_bf16(hi0, lo1, acc01, 0, 0, 0);
        acc01 = __builtin_amdgcn_mfma_f32_16x16x32_bf16(lo0, hi1, acc01, 0, 0, 0);
        acc11 = __builtin_amdgcn_mfma_f32_16x16x32_bf16(hi1, hi1, acc11, 0, 0, 0);
        acc11 = __builtin_amdgcn_mfma_f32_16x16x32_bf16(hi1, lo1, acc11, 0, 0, 0);
        acc11 = __builtin_amdgcn_mfma_f32_16x16x32_bf16(lo1, hi1, acc11, 0, 0, 0);

        sv0 = nv0; sv1 = nv1; sv2 = nv2; sv3 = nv3;
    }

    // flush pooled
#pragma unroll
    for (int j = 0; j < 4; ++j){
        if (pacc[j] != 0.f) atomicAdd(&s_pool[curb][cbase + j], pacc[j]);
    }
    // block-reduce M in LDS
#pragma unroll
    for (int r = 0; r < 4; ++r){
        const int idx = (4 * q + r) * 16 + p;
        atomicAdd(&s_M[0][idx], acc00[r]);
        atomicAdd(&s_M[1][idx], acc01[r]);
        atomicAdd(&s_M[2][idx], acc11[r]);
    }
    __syncthreads();
    {
        const float pv = ((float*)s_pool)[tid];
        if (pv != 0.f) atomicAdd(&ws_pool[tid], pv);
    }
    // global M: striped over MSLICES copies to cut per-address contention
    {
        float* slice = ws_M + (size_t)(blockIdx.x % MSLICES) * 768;
        for (int i = tid; i < 768; i += TPB){
            const float v = ((float*)s_M)[i];
            if (v != 0.f) atomicAdd(slice + i, v);
        }
    }
}

// ---------------------------------------------------------------------------
// R7 pass2: fold BN from (M, mu_f), then single sweep of L3-hot feats doing
// h (folded weights), mask, and pt. Block 0 writes pooled+iou.
// ---------------------------------------------------------------------------
__global__ __launch_bounds__(TPB) void pass2_kernel(
    const float* __restrict__ feats, const int* __restrict__ ws_lb,
    const float* __restrict__ w1,
    const float* __restrict__ gamma, const float* __restrict__ beta,
    const float* __restrict__ w2, const float* __restrict__ b2,
    const float* __restrict__ mw1, const float* __restrict__ mb1,
    const float* __restrict__ mw2, const float* __restrict__ mb2,
    const float* __restrict__ iw, const float* __restrict__ ib,
    const float* __restrict__ ws_pool, const float* __restrict__ ws_M,
    float* __restrict__ pt_out, float* __restrict__ mask_out,
    float* __restrict__ pooled_out, float* __restrict__ iou_out,
    int N, int B)
{
    __shared__ float s_stage[TPB/64][1024];
    __shared__ float s_w[1024];
    __shared__ float s_M2[1024];
    __shared__ float s_mu[32];
    __shared__ float s_var[32];
    __shared__ float s_sc[32];
    __shared__ float s_bp[32];
    __shared__ float s_pooled[256];
    __shared__ int   s_lb[9];

    const int tid  = threadIdx.x;
    const int lane = tid & 63;
    const int wv   = tid >> 6;
    const int p = lane & 15;
    const int q = lane >> 4;

    // load W1 + assemble full 32x32 M from slices
    for (int i = tid; i < 1024; i += TPB) s_w[i] = w1[i];
    for (int i = tid; i < 256; i += TPB){
        float v0 = 0.f, v1 = 0.f, v2 = 0.f;
#pragma unroll
        for (int s = 0; s < MSLICES; ++s){
            v0 += ws_M[(size_t)s * 768 + i];
            v1 += ws_M[(size_t)s * 768 + 256 + i];
            v2 += ws_M[(size_t)s * 768 + 512 + i];
        }
        const int m = i >> 4, n = i & 15;
        s_M2[m * 32 + n] = v0;                   // Q0 full 16x16
        s_M2[(16 + m) * 32 + 16 + n] = v2;       // Q2 full 16x16
        s_M2[m * 32 + 16 + n] = v1;              // Q1 and its mirror
        s_M2[(16 + n) * 32 + m] = v1;
    }
    if (tid < 32){
        float s = 0.f;
        for (int b = 0; b < B; ++b) s += ws_pool[b * 32 + tid];
        s_mu[tid]  = s / (float)N;
        s_var[tid] = 0.f;
    }
    if (tid <= B) s_lb[tid] = ws_lb[tid];
    __syncthreads();

    // w_c^T M w_c partials: thread t handles channel c = t&31, a-chunk t>>5
    {
        const int c = tid & 31, a0 = (tid >> 5) * 4;
        float part = 0.f;
#pragma unroll
        for (int a = a0; a < a0 + 4; ++a){
            float t2 = 0.f;
#pragma unroll
            for (int b = 0; b < 32; ++b) t2 = fmaf(s_w[b * 32 + c], s_M2[a * 32 + b], t2);
            part = fmaf(s_w[a * 32 + c], t2, part);
        }
        atomicAdd(&s_var[c], part);
    }
    __syncthreads();
    if (tid < 32){
        float muh = 0.f;
#pragma unroll
        for (int a = 0; a < 32; ++a) muh = fmaf(s_mu[a], s_w[a * 32 + tid], muh);
        const float var = s_var[tid] / (float)N - muh * muh;
        const float s   = gamma[tid] * rsqrtf(var + 1e-4f);
        s_sc[tid] = s;
        s_bp[tid] = beta[tid] - muh * s;         // b1 cancels exactly
    }
    __syncthreads();

    if (blockIdx.x == 0){
        if (tid < B * 32){
            const int bb = tid >> 5;
            const float cnt = fmaxf((float)(s_lb[bb + 1] - s_lb[bb]), 1.f);
            const float pv = ws_pool[tid] / cnt;
            s_pooled[tid]   = pv;
            pooled_out[tid] = pv;
        }
        __syncthreads();
        if (tid < B){
            float acc = ib[0];
#pragma unroll
            for (int i = 0; i < 32; ++i) acc = fmaf(s_pooled[tid * 32 + i], iw[i], acc);
            iou_out[tid] = acc;
        }
    }

    short8 aw0, aw1, am0, am1;
    floatx4 ci_h0, ci_h1, ci_m0, ci_m1;
    float mw2v[8], w2v[24];
    const float sc0 = s_sc[p], sc1 = s_sc[16 + p];
#pragma unroll
    for (int j = 0; j < 8; ++j){
        const int k = q * 8 + j;
        aw0[j] = (short)bf_rne(s_w[k * 32 + p]      * sc0);
        aw1[j] = (short)bf_rne(s_w[k * 32 + 16 + p] * sc1);
        am0[j] = (short)bf_rne(mw1[k * 32 + p]);
        am1[j] = (short)bf_rne(mw1[k * 32 + 16 + p]);
    }
#pragma unroll
    for (int r = 0; r < 4; ++r){
        const int c0 = q * 4 + r, c1 = 16 + q * 4 + r;
        ci_h0[r] = s_bp[c0];  ci_h1[r] = s_bp[c1];
        ci_m0[r] = mb1[c0];   ci_m1[r] = mb1[c1];
        mw2v[r] = mw2[c0];    mw2v[4 + r] = mw2[c1];
    }
#pragma unroll
    for (int i = 0; i < 8; ++i){
        const int ch = (i >> 2) * 16 + q * 4 + (i & 3);
        w2v[i]      = w2[ch * 3 + 0];
        w2v[8 + i]  = w2[ch * 3 + 1];
        w2v[16 + i] = w2[ch * 3 + 2];
    }
    const float b2v0 = b2[0], b2v1 = b2[1], b2v2 = b2[2];
    const float mb2s = mb2[0];

    const int ngroups = (N + 31) >> 5;
    const int nw  = gridDim.x * (TPB / 64);
    const int wid = blockIdx.x * (TPB / 64) + wv;
    const int g0  = (int)((long)wid       * ngroups / nw);
    const int gE  = (int)((long)(wid + 1) * ngroups / nw);

    float* sw = &s_stage[wv][0];
    const int wrow = lane >> 3;
    const int wg   = (lane & 7) ^ wrow;
    const int wo0 = ( 0 + wrow) * 32 + (wg << 2);
    const int wo1 = ( 8 + wrow) * 32 + (wg << 2);
    const int wo2 = (16 + wrow) * 32 + (wg << 2);
    const int wo3 = (24 + wrow) * 32 + (wg << 2);
    const int e = p & 7;
    const int ra0 = p * 32        + ((((q << 1)    ) ^ e) << 2);
    const int ra1 = p * 32        + ((((q << 1) + 1) ^ e) << 2);
    const int rb0 = (16 + p) * 32 + ((((q << 1)    ) ^ e) << 2);
    const int rb1 = (16 + p) * 32 + ((((q << 1) + 1) ^ e) << 2);

    floatx4 sv0 = {0,0,0,0}, sv1 = {0,0,0,0}, sv2 = {0,0,0,0}, sv3 = {0,0,0,0};
    if (g0 < gE){
        const float* gp = feats + ((size_t)g0 << 10) + (lane << 2);
        const int r = (g0 << 5) + wrow;
        if (r + 24 < N){
            sv0 = *(const floatx4*)(gp);
            sv1 = *(const floatx4*)(gp + 256);
            sv2 = *(const floatx4*)(gp + 512);
            sv3 = *(const floatx4*)(gp + 768);
        } else {
            if (r      < N) sv0 = *(const floatx4*)(gp);
            if (r +  8 < N) sv1 = *(const floatx4*)(gp + 256);
            if (r + 16 < N) sv2 = *(const floatx4*)(gp + 512);
            if (r + 24 < N) sv3 = *(const floatx4*)(gp + 768);
        }
    }

    for (int g = g0; g < gE; ++g){
        *(floatx4*)(sw + wo0) = sv0;
        *(floatx4*)(sw + wo1) = sv1;
        *(floatx4*)(sw + wo2) = sv2;
        *(floatx4*)(sw + wo3) = sv3;

        floatx4 nv0 = {0,0,0,0}, nv1 = {0,0,0,0}, nv2 = {0,0,0,0}, nv3 = {0,0,0,0};
        if (g + 1 < gE){
            const float* gp = feats + ((size_t)(g + 1) << 10) + (lane << 2);
            const int r = ((g + 1) << 5) + wrow;
            if (r + 24 < N){
                nv0 = *(const floatx4*)(gp);
                nv1 = *(const floatx4*)(gp + 256);
                nv2 = *(const floatx4*)(gp + 512);
                nv3 = *(const floatx4*)(gp + 768);
            } else {
                if (r      < N) nv0 = *(const floatx4*)(gp);
                if (r +  8 < N) nv1 = *(const floatx4*)(gp + 256);
                if (r + 16 < N) nv2 = *(const floatx4*)(gp + 512);
                if (r + 24 < N) nv3 = *(const floatx4*)(gp + 768);
            }
        }

        const floatx4 vA0 = *(const floatx4*)(sw + ra0);
        const floatx4 vA1 = *(const floatx4*)(sw + ra1);
        const floatx4 vB0 = *(const floatx4*)(sw + rb0);
        const floatx4 vB1 = *(const floatx4*)(sw + rb1);

        short8 bfA, bfB;
        {
            unsigned* ba = (unsigned*)&bfA;
            ba[0] = pack_bf(vA0[0], vA0[1]); ba[1] = pack_bf(vA0[2], vA0[3]);
            ba[2] = pack_bf(vA1[0], vA1[1]); ba[3] = pack_bf(vA1[2], vA1[3]);
            unsigned* bb = (unsigned*)&bfB;
            bb[0] = pack_bf(vB0[0], vB0[1]); bb[1] = pack_bf(vB0[2], vB0[3]);
            bb[2] = pack_bf(vB1[0], vB1[1]); bb[3] = pack_bf(vB1[2], vB1[3]);
        }

        const floatx4 cA0 = __builtin_amdgcn_mfma_f32_16x16x32_bf16(aw0, bfA, ci_h0, 0, 0, 0);
        const floatx4 cA1 = __builtin_amdgcn_mfma_f32_16x16x32_bf16(aw1, bfA, ci_h1, 0, 0, 0);
        const floatx4 mA0 = __builtin_amdgcn_mfma_f32_16x16x32_bf16(am0, bfA, ci_m0, 0, 0, 0);
        const floatx4 mA1 = __builtin_amdgcn_mfma_f32_16x16x32_bf16(am1, bfA, ci_m1, 0, 0, 0);
        const floatx4 cB0 = __builtin_amdgcn_mfma_f32_16x16x32_bf16(aw0, bfB, ci_h0, 0, 0, 0);
        const floatx4 cB1 = __builtin_amdgcn_mfma_f32_16x16x32_bf16(aw1, bfB, ci_h1, 0, 0, 0);
        const floatx4 mB0 = __builtin_amdgcn_mfma_f32_16x16x32_bf16(am0, bfB, ci_m0, 0, 0, 0);
        const floatx4 mB1 = __builtin_amdgcn_mfma_f32_16x16x32_bf16(am1, bfB, ci_m1, 0, 0, 0);

        float sA0 = 0.f, sA1 = 0.f, sA2 = 0.f, sB0 = 0.f, sB1 = 0.f, sB2 = 0.f;
        float tmA = 0.f, tmB = 0.f;
#pragma unroll
        for (int r = 0; r < 4; ++r){
            const float a0 = fmaxf(cA0[r], 0.f);
            const float a1 = fmaxf(cA1[r], 0.f);
            sA0 = fmaf(a0, w2v[r],      sA0); sA0 = fmaf(a1, w2v[4 + r],  sA0);
            sA1 = fmaf(a0, w2v[8 + r],  sA1); sA1 = fmaf(a1, w2v[12 + r], sA1);
            sA2 = fmaf(a0, w2v[16 + r], sA2); sA2 = fmaf(a1, w2v[20 + r], sA2);
            const float b0 = fmaxf(cB0[r], 0.f);
            const float b1v = fmaxf(cB1[r], 0.f);
            sB0 = fmaf(b0, w2v[r],      sB0); sB0 = fmaf(b1v, w2v[4 + r],  sB0);
            sB1 = fmaf(b0, w2v[8 + r],  sB1); sB1 = fmaf(b1v, w2v[12 + r], sB1);
            sB2 = fmaf(b0, w2v[16 + r], sB2); sB2 = fmaf(b1v, w2v[20 + r], sB2);
            tmA = fmaf(fmaxf(mA0[r], 0.f), mw2v[r],     tmA);
            tmA = fmaf(fmaxf(mA1[r], 0.f), mw2v[4 + r], tmA);
            tmB = fmaf(fmaxf(mB0[r], 0.f), mw2v[r],     tmB);
            tmB = fmaf(fmaxf(mB1[r], 0.f), mw2v[4 + r], tmB);
        }
        sA0 += __shfl_xor(sA0, 16, 64); sA0 += __shfl_xor(sA0, 32, 64);
        sA1 += __shfl_xor(sA1, 16, 64); sA1 += __shfl_xor(sA1, 32, 64);
        sA2 += __shfl_xor(sA2, 16, 64); sA2 += __shfl_xor(sA2, 32, 64);
        sB0 += __shfl_xor(sB0, 16, 64); sB0 += __shfl_xor(sB0, 32, 64);
        sB1 += __shfl_xor(sB1, 16, 64); sB1 += __shfl_xor(sB1, 32, 64);
        sB2 += __shfl_xor(sB2, 16, 64); sB2 += __shfl_xor(sB2, 32, 64);
        tmA += __shfl_xor(tmA, 16, 64); tmA += __shfl_xor(tmA, 32, 64);
        tmB += __shfl_xor(tmB, 16, 64); tmB += __shfl_xor(tmB, 32, 64);

        const int r0 = g << 5;
        const int rA = r0 + p, rB = r0 + 16 + p;
        if (lane < 48 && rA < N){
            const float val = (q == 0) ? (sA0 + b2v0) : ((q == 1) ? (sA1 + b2v1) : (sA2 + b2v2));
            pt_out[(size_t)rA * 3 + q] = val;
        }
        if (lane < 48 && rB < N){
            const float val = (q == 0) ? (sB0 + b2v0) : ((q == 1) ? (sB1 + b2v1) : (sB2 + b2v2));
            pt_out[(size_t)rB * 3 + q] = val;
        }
        if (q == 0 && rA < N) mask_out[rA] = tmA + mb2s;
        if (q == 0 && rB < N) mask_out[rB] = tmB + mb2s;

        sv0 = nv0; sv1 = nv1; sv2 = nv2; sv3 = nv3;
    }
}

extern "C" void kernel_launch(void* const* d_in, const int* in_sizes, int n_in,
                              void* d_out, int out_size, void* d_ws, size_t ws_size,
                              hipStream_t stream) {
    const float* feats = (const float*)d_in[0];
    const int*   bidx  = (const int*)d_in[1];
    const float* w1    = (const float*)d_in[2];
    const float* b1    = (const float*)d_in[3];   // unused: cancels in BN fold
    const float* gamma = (const float*)d_in[4];
    const float* beta  = (const float*)d_in[5];
    const float* w2    = (const float*)d_in[6];
    const float* b2    = (const float*)d_in[7];
    const float* mw1   = (const float*)d_in[8];
    const float* mb1   = (const float*)d_in[9];
    const float* mw2   = (const float*)d_in[10];
    const float* mb2   = (const float*)d_in[11];
    const float* iw    = (const float*)d_in[12];
    const float* ib    = (const float*)d_in[13];
    (void)b1;

    const int N = in_sizes[0] / 32;
    const int B = (out_size - 4 * N) / 33;   // out = 3N + N + 32B + B

    float* out    = (float*)d_out;
    float* pt     = out;                       // [N,3]
    float* mask   = out + (size_t)3 * N;       // [N,1]
    float* pooled = out + (size_t)4 * N;       // [B,32]
    float* iou    = pooled + (size_t)B * 32;   // [B,1]

    float* ws      = (float*)d_ws;
    float* ws_pool = ws;                                   // B*32 = 256
    float* ws_M    = ws + 256;                             // MSLICES*768
    int*   ws_lb   = (int*)(ws + 256 + MSLICES * 768);     // B+1 ints

    (void)hipMemsetAsync(ws, 0, (size_t)(256 + MSLICES * 768) * sizeof(float), stream);

    lb_kernel<<<1, 64, 0, stream>>>(bidx, ws_lb, N, B);
    pass1_kernel<<<GRID1, TPB, 0, stream>>>(feats, ws_lb, ws_pool, ws_M, N, B);
    pass2_kernel<<<GRID2, TPB, 0, stream>>>(feats, ws_lb, w1, gamma, beta, w2, b2,
                                            mw1, mb1, mw2, mb2, iw, ib,
                                            ws_pool, ws_M,
                                            pt, mask, pooled, iou, N, B);
}